// Round 4
// baseline (377.151 us; speedup 1.0000x reference)
//
#include <hip/hip_runtime.h>
#include <hip/hip_bf16.h>
#include <cstdint>

#define DEVINL __device__ __forceinline__

typedef __attribute__((ext_vector_type(8))) short bf16x8;
typedef __attribute__((ext_vector_type(4))) float f32x4;

DEVINL unsigned short f2bf(float f) {
    union { float f; unsigned u; } v; v.f = f;
    unsigned r = v.u + 0x7fffu + ((v.u >> 16) & 1u);   // RNE
    return (unsigned short)(r >> 16);
}
DEVINL float bf2f(unsigned short h) {
    union { unsigned u; float f; } v; v.u = ((unsigned)h) << 16;
    return v.f;
}

constexpr int BN = 256, BK = 32;
constexpr int PITCH = 40;   // u16/row = 80B; b128 reads cover all 32 banks exactly twice (free)
constexpr int NSP = 256;    // H*W

// ---------------------------------------------------------------------------
// Transpose + bf16 convert: x[b][2048][256] f32 -> xT[b][256][2048] bf16.
__global__ __launch_bounds__(256)
void xpose(const float* __restrict__ x, unsigned short* __restrict__ xT)
{
    __shared__ float sh[64][65];
    const int b   = blockIdx.y;
    const int kt  = blockIdx.x & 31;     // 2048/64
    const int ntb = blockIdx.x >> 5;     // 256/64
    const int k0 = kt * 64, n0 = ntb * 64;

    const int r = threadIdx.x >> 4;          // 0..15
    const int c = (threadIdx.x & 15) * 4;    // 0..60

    const float* xb = x + ((size_t)b * 2048 + k0) * 256 + n0;
#pragma unroll
    for (int i = 0; i < 4; ++i) {
        float4 v = *(const float4*)(xb + (size_t)(r + 16 * i) * 256 + c);
        sh[r + 16 * i][c + 0] = v.x;
        sh[r + 16 * i][c + 1] = v.y;
        sh[r + 16 * i][c + 2] = v.z;
        sh[r + 16 * i][c + 3] = v.w;
    }
    __syncthreads();
#pragma unroll
    for (int i = 0; i < 4; ++i) {
        const int rr = r + 16 * i;           // n within tile
        ushort4 o;
        o.x = f2bf(sh[c + 0][rr]);
        o.y = f2bf(sh[c + 1][rr]);
        o.z = f2bf(sh[c + 2][rr]);
        o.w = f2bf(sh[c + 3][rr]);
        *(ushort4*)(xT + ((size_t)b * NSP + n0 + rr) * 2048 + k0 + c) = o;
    }
}

// ---------------------------------------------------------------------------
// Y^T[b][n][m] = sigmoid( sum_k W[b][m][k]*XT[b][n][k] + bias[b][m] ), bf16 out.
// BN=256 (full N): W panel fetched once. 512 thr = 8 waves, WM x WN wave grid.
// Grid: x = b (sample) so a sample's m-blocks share an XCD; y = m-tile.
// Epilogue: LDS-staged re-layout -> 256B-contiguous row stores (kills the 8-13x
// partial-line write amplification of direct fragment scatter).
template<int BM, int WM, int WN>
__global__ __launch_bounds__(512, 4)
void fc_gemm(const float* __restrict__ Wt, const float* __restrict__ bias,
             const unsigned short* __restrict__ X, unsigned short* __restrict__ Yt,
             int M, int K)
{
    constexpr int TM = BM / WM;     // 64
    constexpr int TN = BN / WN;     // 64 or 32
    constexpr int AM = TM / 16;     // 4
    constexpr int AN = TN / 16;     // 4 or 2
    constexpr int AI = BM / 64;     // A-staging float4s per thread (2 or 1)
    constexpr int EPP = BM + 8;     // epilogue LDS pitch (u16)

    const int b  = blockIdx.x;
    const int m0 = blockIdx.y * BM;

    // One raw LDS pool: staging (double-buffered sA+sB) reused by epilogue tile.
    __shared__ __align__(16) unsigned short smem[(2 * BM + 2 * BN) * PITCH];
    unsigned short* sA0 = smem;                       // [2][BM*PITCH]
    unsigned short* sB0 = smem + 2 * BM * PITCH;      // [2][BN*PITCH]

    const int tid  = threadIdx.x;
    const int lane = tid & 63;
    const int wid  = tid >> 6;
    const int wm   = (wid / WN) * TM;
    const int wn   = (wid % WN) * TN;
    const int fr   = lane & 15;
    const int fo   = (lane >> 4) * 8;

    // A staging: BM x 32 fp32 -> bf16
    const int am = (AI == 2) ? (tid >> 2) : (tid >> 3);
    const int ac = (AI == 2) ? (tid & 3) * 4 : (tid & 7) * 4;
    const float* Wb = Wt + (size_t)b * M * K + (size_t)m0 * K;

    // B staging: 256 x 32 bf16
    const int bn = tid >> 1;
    const int bc = (tid & 1) * 16;
    const unsigned short* Xb = X + (size_t)b * NSP * K;

    float4 aR[AI];
    uint4  bR[2];

    auto loadA = [&](int k0) {
#pragma unroll
        for (int i = 0; i < AI; ++i)
            aR[i] = *(const float4*)(Wb + (size_t)am * K + k0 + ac + i * 16);
    };
    auto loadB = [&](int k0) {
#pragma unroll
        for (int i = 0; i < 2; ++i)
            bR[i] = *(const uint4*)(Xb + (size_t)bn * K + k0 + bc + i * 8);
    };
    auto storeA = [&](int buf) {
        unsigned short* s = sA0 + buf * BM * PITCH;
#pragma unroll
        for (int i = 0; i < AI; ++i) {
            ushort4 p;
            p.x = f2bf(aR[i].x); p.y = f2bf(aR[i].y);
            p.z = f2bf(aR[i].z); p.w = f2bf(aR[i].w);
            *(ushort4*)&s[am * PITCH + ac + i * 16] = p;
        }
    };
    auto storeB = [&](int buf) {
        unsigned short* s = sB0 + buf * BN * PITCH;
#pragma unroll
        for (int i = 0; i < 2; ++i)
            *(uint4*)&s[bn * PITCH + bc + i * 8] = bR[i];
    };

    f32x4 acc[AM][AN] = {};

    loadA(0); loadB(0);
    storeA(0); storeB(0);
    __syncthreads();

    const int NT = K / BK;
    int cur = 0;
#pragma unroll 1
    for (int t = 0; t < NT; ++t) {
        if (t + 1 < NT) { loadA((t + 1) * BK); loadB((t + 1) * BK); }  // in flight under MFMA

        const unsigned short* a = sA0 + cur * BM * PITCH;
        const unsigned short* bb = sB0 + cur * BN * PITCH;
        bf16x8 af[AM], bfr[AN];
#pragma unroll
        for (int i = 0; i < AM; ++i)
            af[i] = *(const bf16x8*)&a[(wm + i * 16 + fr) * PITCH + fo];
#pragma unroll
        for (int i = 0; i < AN; ++i)
            bfr[i] = *(const bf16x8*)&bb[(wn + i * 16 + fr) * PITCH + fo];
#pragma unroll
        for (int mi = 0; mi < AM; ++mi)
#pragma unroll
            for (int ni = 0; ni < AN; ++ni)
                acc[mi][ni] = __builtin_amdgcn_mfma_f32_16x16x32_bf16(af[mi], bfr[ni], acc[mi][ni], 0, 0, 0);

        if (t + 1 < NT) { storeA(cur ^ 1); storeB(cur ^ 1); }
        __syncthreads();
        cur ^= 1;
    }

    // ---- Epilogue: bias+sigmoid+pack, stage [128 n][BM m] in LDS, store full rows.
    const int hi4 = (lane >> 4) * 4;
#pragma unroll 1
    for (int ph = 0; ph < 2; ++ph) {
        if ((wn >> 7) == ph) {
#pragma unroll
            for (int mi = 0; mi < AM; ++mi) {
#pragma unroll
                for (int ni = 0; ni < AN; ++ni) {
                    const int r  = (wn & 127) + ni * 16 + fr;   // n within phase
                    const int mb = wm + mi * 16 + hi4;          // m within block
                    f32x4 v = acc[mi][ni];
                    ushort4 o;
#pragma unroll
                    for (int q = 0; q < 4; ++q) {
                        float yv = v[q] + bias[(size_t)b * M + m0 + mb + q];
                        yv = 1.0f / (1.0f + __expf(-yv));
                        ((unsigned short*)&o)[q] = f2bf(yv);
                    }
                    *(ushort4*)&smem[r * EPP + mb] = o;
                }
            }
        }
        __syncthreads();
        // Cooperative store: 16B/lane, 256B-contiguous segments per n-row.
        constexpr int TPR = BM / 8;           // threads per row
        constexpr int RPI = 512 / TPR;        // rows per iteration
        const int r = tid / TPR;
        const int c = (tid % TPR) * 8;
#pragma unroll
        for (int it = 0; it < 128 / RPI; ++it) {
            const int rr = r + it * RPI;
            uint4 v = *(const uint4*)&smem[rr * EPP + c];
            *(uint4*)&Yt[((size_t)b * NSP + ph * 128 + rr) * M + m0 + c] = v;
        }
        __syncthreads();   // protect smem before next phase overwrites
    }
}

// Layer 5: out[b][n] = sum_k act4T[b][n][k] * w5[b][k] + b5[b]   (no sigmoid)
__global__ void fc_final(const unsigned short* __restrict__ A4,
                         const float* __restrict__ W5,
                         const float* __restrict__ B5,
                         float* __restrict__ out)
{
    const int b = blockIdx.x;
    const int t = threadIdx.x;  // 0..255 spatial
    const unsigned short* row = A4 + ((size_t)b * NSP + t) * 128;
    const float* w = W5 + (size_t)b * 128;
    float acc = B5[b];
#pragma unroll
    for (int k = 0; k < 128; k += 8) {
        uint4 v = *(const uint4*)(row + k);
        acc += bf2f((unsigned short)(v.x & 0xffff)) * w[k+0];
        acc += bf2f((unsigned short)(v.x >> 16))    * w[k+1];
        acc += bf2f((unsigned short)(v.y & 0xffff)) * w[k+2];
        acc += bf2f((unsigned short)(v.y >> 16))    * w[k+3];
        acc += bf2f((unsigned short)(v.z & 0xffff)) * w[k+4];
        acc += bf2f((unsigned short)(v.z >> 16))    * w[k+5];
        acc += bf2f((unsigned short)(v.w & 0xffff)) * w[k+6];
        acc += bf2f((unsigned short)(v.w >> 16))    * w[k+7];
    }
    out[b * NSP + t] = acc;
}

extern "C" void kernel_launch(void* const* d_in, const int* in_sizes, int n_in,
                              void* d_out, int out_size, void* d_ws, size_t ws_size,
                              hipStream_t stream)
{
    const float* x  = (const float*)d_in[0];
    const float* w1 = (const float*)d_in[1];
    const float* b1 = (const float*)d_in[2];
    const float* w2 = (const float*)d_in[3];
    const float* b2 = (const float*)d_in[4];
    const float* w3 = (const float*)d_in[5];
    const float* b3 = (const float*)d_in[6];
    const float* w4 = (const float*)d_in[7];
    const float* b4 = (const float*)d_in[8];
    const float* w5 = (const float*)d_in[9];
    const float* b5 = (const float*)d_in[10];

    unsigned short* ws0 = (unsigned short*)d_ws;

    // u16-element offsets. xT dead after L1 -> act2/3/4 reuse its region.
    const size_t XT = (size_t)64 * 256 * 2048;  // 33.55M u16 (67.1 MB)
    unsigned short* xT   = ws0;
    unsigned short* act1 = ws0 + XT;
    unsigned short* act2 = ws0;
    unsigned short* act3 = ws0 + (size_t)64 * 256 * 512;
    unsigned short* act4 = ws0 + (size_t)64 * 256 * (512 + 256);

    xpose<<<dim3(128, 64), dim3(256), 0, stream>>>(x, xT);
    fc_gemm<128, 2, 4><<<dim3(64, 8), dim3(512), 0, stream>>>(w1, b1, xT,   act1, 1024, 2048);
    fc_gemm<128, 2, 4><<<dim3(64, 4), dim3(512), 0, stream>>>(w2, b2, act1, act2,  512, 1024);
    fc_gemm< 64, 1, 8><<<dim3(64, 4), dim3(512), 0, stream>>>(w3, b3, act2, act3,  256,  512);
    fc_gemm< 64, 1, 8><<<dim3(64, 2), dim3(512), 0, stream>>>(w4, b4, act3, act4,  128,  256);
    fc_final<<<dim3(64), dim3(256), 0, stream>>>(act4, w5, b5, (float*)d_out);
}